// Round 15
// baseline (3508.697 us; speedup 1.0000x reference)
//
#include <hip/hip_runtime.h>
#include <math.h>

// Problem: MPMatcher  S=6, B=16, L=8, M=256, K=128
// Phase 1 (PASSING, DO NOT TOUCH): cost f32, ocml logf, *(1/6) reciprocal mean.
// Phase 2: reference's buggy greedy walk, f64-exact. R14 = R13 with the DPP
//   ladders expanded to literal-constant stages (builtin requires ICE args):
//   - depth-4 ring queue of (v, j, u[row], row-data); pop = register selects
//   - refill = ONE value-max ladder per iter when depth<4, at loop bottom
//   - eager 2-deep fill at walk start
//   - real-win path identical to R11

#define S_ 6
#define B_ 16
#define L_ 8
#define M_ 256
#define K_ 128

// ---------------------------------------------------------------- cost kernel
__global__ void cost_kernel(const float* __restrict__ mp,   // (6,16,8,256,2)
                            const float* __restrict__ mv,   // (6,16,256,1)
                            const float* __restrict__ gt,   // (6,16,128,2)
                            const float* __restrict__ gv,   // (6,16,128,1)
                            float* __restrict__ cost)       // (16,256,128)
{
#pragma clang fp contract(off)
    const int b = blockIdx.x;
    const int m = blockIdx.y;
    const int k = threadIdx.x;

    float accS = 0.0f;
    for (int s = 0; s < S_; ++s) {
        const int sb = s * B_ + b;
        const float gx = gt[(sb * K_ + k) * 2 + 0];
        const float gy = gt[(sb * K_ + k) * 2 + 1];
        float accL = 0.0f;
#pragma unroll
        for (int l = 0; l < L_; ++l) {
            const int base = ((sb * L_ + l) * M_ + m) * 2;
            const float dx = fabsf(mp[base + 0] - gx);
            const float dy = fabsf(mp[base + 1] - gy);
            const float diff = dx + dy;
            const float dl = (float)(L_ - (l + 1)) * 0.05f;
            const float t = diff - dl;
            accL += fmaxf(t, 0.0f);
        }
        const float meanL = accL * 0.125f;
        const float mvv = mv[sb * M_ + m];
        const float gtv = gv[sb * K_ + k];
        const float lp = -logf(mvv);
        const float ln = -logf(1.0f - mvv);
        const float val = (gtv != 0.0f) ? (5.0f * meanL + lp) : ln;
        accS += val;
    }
    cost[(b * M_ + m) * K_ + k] = accS * (1.0f / 6.0f);
}

// --------------------------------------------------------------- bit helpers
__device__ __forceinline__ double bits2d(int lo, int hi) {
    const unsigned long long u =
        ((unsigned long long)(unsigned)hi << 32) | (unsigned)lo;
    return __longlong_as_double((long long)u);
}
__device__ __forceinline__ void d2bits(double d, int& lo, int& hi) {
    const unsigned long long u = (unsigned long long)__double_as_longlong(d);
    lo = (int)(u & 0xffffffffull);
    hi = (int)(u >> 32);
}

// one DPP min/max stage with LITERAL ctrl/rm (builtin needs constant ints)
#define MIN_STAGE(lo, hi, CTRL, RM)                                              \
{                                                                                \
    const int nlo = __builtin_amdgcn_update_dpp(lo, lo, CTRL, RM, 0xf, false);   \
    const int nhi = __builtin_amdgcn_update_dpp(hi, hi, CTRL, RM, 0xf, false);   \
    const double m2 = fmin(bits2d(lo, hi), bits2d(nlo, nhi));                    \
    d2bits(m2, lo, hi);                                                          \
}
#define MAX_STAGE(lo, hi, CTRL, RM)                                              \
{                                                                                \
    const int nlo = __builtin_amdgcn_update_dpp(lo, lo, CTRL, RM, 0xf, false);   \
    const int nhi = __builtin_amdgcn_update_dpp(hi, hi, CTRL, RM, 0xf, false);   \
    const double m2 = fmax(bits2d(lo, hi), bits2d(nlo, nhi));                    \
    d2bits(m2, lo, hi);                                                          \
}
#define LADDER_MIN(lo, hi)          \
    MIN_STAGE(lo, hi, 0x111, 0xf)   \
    MIN_STAGE(lo, hi, 0x112, 0xf)   \
    MIN_STAGE(lo, hi, 0x114, 0xf)   \
    MIN_STAGE(lo, hi, 0x118, 0xf)   \
    MIN_STAGE(lo, hi, 0x142, 0xa)   \
    MIN_STAGE(lo, hi, 0x143, 0xc)
#define LADDER_MAX(lo, hi)          \
    MAX_STAGE(lo, hi, 0x111, 0xf)   \
    MAX_STAGE(lo, hi, 0x112, 0xf)   \
    MAX_STAGE(lo, hi, 0x114, 0xf)   \
    MAX_STAGE(lo, hi, 0x118, 0xf)   \
    MAX_STAGE(lo, hi, 0x142, 0xa)   \
    MAX_STAGE(lo, hi, 0x143, 0xc)

// ------------------------------------------------------------- matcher kernel
// One wave per batch. Lane owns real cols j=2*lane+1, 2*lane+2 (slots 0,1)
// and dummy cols j=2*lane+129, 2*lane+130 (slots 2,3).
__global__ __launch_bounds__(64, 1) void match_kernel(const float* __restrict__ cost,
                                                      int* __restrict__ out)
{
#pragma clang fp contract(off)
    const int b = blockIdx.x;
    const int lane = threadIdx.x;   // 0..63
    const float* C = cost + (size_t)b * M_ * K_;
    const double INF = __builtin_inf();
    const double NINF = -__builtin_inf();
    const int BIG = 0x7fffffff;

    __shared__ float  C_lds[M_ * K_];   // 128 KB cost slab (row-major, = global)
    __shared__ double u_lds[257];       // u[0..256], 1-based rows
    __shared__ int    p_lds[257];       // p[j] = row matched to col j; 0 = free

    for (int t = lane; t < (M_ * K_) / 4; t += 64)
        ((float4*)C_lds)[t] = ((const float4*)C)[t];

    // rows 1..128 pre-matched to dummy cols 129..256 (exact, proven R8)
    for (int t = lane; t < 257; t += 64) {
        u_lds[t] = 0.0;
        p_lds[t] = (t >= 129) ? (t - 128) : 0;
    }
    __syncthreads();

    double v0 = 0.0, v1 = 0.0, v2 = 0.0, v3 = 0.0;  // column potentials

    for (int i = 129; i <= 256; ++i) {
        // ---- row start snapshots (validity proven R8-R11)
        int used = 0;
        int dq = 0;                        // dummy slots queued-or-popped
        const int pj0 = p_lds[2 * lane + 1];
        const int pj1 = p_lds[2 * lane + 2];
        double ur0 = u_lds[pj0], ur1 = u_lds[pj1];
        double ur2 = u_lds[2 * lane + 1];  // p[dummy 2l+129] == 2l+1 forever
        double ur3 = u_lds[2 * lane + 2];
        const double up0 = ur0, up1 = ur1;

        // ---- dummy priority queue: ring of 4 (kv, kj, ku, kcx, kcy)
        double kv0 = 0, kv1 = 0, kv2q = 0, kv3q = 0;
        int    kj0 = 0, kj1 = 0, kj2q = 0, kj3q = 0;
        double ku0 = 0, ku1 = 0, ku2q = 0, ku3q = 0;
        float  kcx0 = 0, kcx1 = 0, kcx2 = 0, kcx3 = 0;
        float  kcy0 = 0, kcy1 = 0, kcy2 = 0, kcy3 = 0;
        int head = 0, tail = 0;

        // refill: append argmax-v (first-j) over eligible dummies + its loads
        auto refill = [&]() {
            const bool e2 = !(dq & 1), e3 = !(dq & 2);
            double bb = e2 ? v2 : NINF;
            if (e3 && (v3 > bb)) bb = v3;
            int lo, hi; d2bits(bb, lo, hi);
            LADDER_MAX(lo, hi)
            const double rv = bits2d(__builtin_amdgcn_readlane(lo, 63),
                                     __builtin_amdgcn_readlane(hi, 63));
            if (rv == NINF) return;        // pool exhausted
            int cand = BIG;
            if (e3 && (v3 == rv)) cand = 2 * lane + 130;
            if (e2 && (v2 == rv)) cand = 2 * lane + 129;  // prefer smaller j
            const unsigned long long bl = __ballot(cand != BIG);
            const int rj = __builtin_amdgcn_readlane(cand, (int)__builtin_ctzll(bl));
            const int olr = (rj - 129) >> 1, slr = (rj - 129) & 1;
            if (lane == olr) dq |= (1 << slr);
            const double kun = u_lds[rj - 128];            // uniform addr
            const float2 kcc = *(const float2*)(C_lds + (rj - 129) * K_ + 2 * lane);
            const int ts = tail & 3;
            if (ts == 0) { kv0 = rv; kj0 = rj; ku0 = kun; kcx0 = kcc.x; kcy0 = kcc.y; }
            else if (ts == 1) { kv1 = rv; kj1 = rj; ku1 = kun; kcx1 = kcc.x; kcy1 = kcc.y; }
            else if (ts == 2) { kv2q = rv; kj2q = rj; ku2q = kun; kcx2 = kcc.x; kcy2 = kcc.y; }
            else { kv3q = rv; kj3q = rj; ku3q = kun; kcx3 = kcc.x; kcy3 = kcc.y; }
            tail++;
        };
        refill();
        refill();

        float2 cc = *(const float2*)(C_lds + (i - 1) * K_ + 2 * lane);
        double u_i0 = 0.0;
        int j1 = 0;
        double usum = 0.0;

        for (;;) {
            // real candidates (exact ref op order, f64)
            double cd0 = ((double)cc.x - u_i0) - v0;
            double cd1 = ((double)cc.y - u_i0) - v1;
            if (used & 1) cd0 = INF;
            if (used & 2) cd1 = INF;
            double bv = fmin(cd0, cd1);
            int lo, hi; d2bits(bv, lo, hi);
            LADDER_MIN(lo, hi)
            const double Rmin = bits2d(__builtin_amdgcn_readlane(lo, 63),
                                       __builtin_amdgcn_readlane(hi, 63));

            // dummy head: Dmin = (0 - u) - v_head (ref op order; head = argmax v)
            const int qn = tail - head;
            const int hs = head & 3;
            const double kvh = (hs == 0) ? kv0 : (hs == 1) ? kv1 : (hs == 2) ? kv2q : kv3q;
            const double Dmin = (qn > 0) ? ((0.0 - u_i0) - kvh) : INF;

            const double delta = fmin(Rmin, Dmin);
            const bool realw = (Rmin <= Dmin);   // tie -> real (smaller j)

            if (realw) {
                // first-index among real achievers (cd == delta)
                int jr = BIG;
                if (cd1 == delta) jr = 2 * lane + 2;
                if (cd0 == delta) jr = 2 * lane + 1;
                const unsigned long long bb2 = __ballot(jr != BIG);
                j1 = __builtin_amdgcn_readlane(jr, (int)__builtin_ctzll(bb2));
                const int ol = (j1 - 1) >> 1, sl = (j1 - 1) & 1;
                const int psel = sl ? pj1 : pj0;
                const int i0n = __builtin_amdgcn_readlane(psel, ol);
                // speculative next-row load ASAP (unused on break)
                const int rown = (i0n > 0 ? i0n : 1) - 1;
                const float2 ccn = *(const float2*)(C_lds + rown * K_ + 2 * lane);
                // shadow: potential updates (ref order)
                usum += delta;
                if (used & 1) { ur0 += delta; v0 -= delta; }
                if (used & 2) { ur1 += delta; v1 -= delta; }
                if (used & 4) { ur2 += delta; v2 -= delta; }
                if (used & 8) { ur3 += delta; v3 -= delta; }
                const double usel = sl ? up1 : up0;
                int ulo, uhi; d2bits(usel, ulo, uhi);
                const double u_n = bits2d(__builtin_amdgcn_readlane(ulo, ol),
                                          __builtin_amdgcn_readlane(uhi, ol));
                if (i0n == 0) break;       // free real col -> augment
                if (lane == ol) used |= (1 << sl);
                u_i0 = u_n;
                cc = ccn;
            } else {
                // dummy pop: all state already in registers
                const int kjh = (hs == 0) ? kj0 : (hs == 1) ? kj1 : (hs == 2) ? kj2q : kj3q;
                const double kuh = (hs == 0) ? ku0 : (hs == 1) ? ku1 : (hs == 2) ? ku2q : ku3q;
                const float ccx = (hs == 0) ? kcx0 : (hs == 1) ? kcx1 : (hs == 2) ? kcx2 : kcx3;
                const float ccy = (hs == 0) ? kcy0 : (hs == 1) ? kcy1 : (hs == 2) ? kcy2 : kcy3;
                j1 = kjh;
                head++;
                // updates (ref order; j1 marked used for NEXT iter, per ref)
                usum += delta;
                if (used & 1) { ur0 += delta; v0 -= delta; }
                if (used & 2) { ur1 += delta; v1 -= delta; }
                if (used & 4) { ur2 += delta; v2 -= delta; }
                if (used & 8) { ur3 += delta; v3 -= delta; }
                const int ol = (j1 - 129) >> 1, sl = 2 + ((j1 - 129) & 1);
                if (lane == ol) used |= (1 << sl);
                u_i0 = kuh;
                cc.x = ccx; cc.y = ccy;
            }

            // top up the queue (off critical path; interleaves with next ladder)
            if (tail - head < 4) refill();
        }

        // ---- commit: marked slots write their running u; lane 0 augments
        __syncthreads();
        if (used & 1) u_lds[pj0] = ur0;
        if (used & 2) u_lds[pj1] = ur1;
        if (used & 4) u_lds[2 * lane + 1] = ur2;
        if (used & 8) u_lds[2 * lane + 2] = ur3;
        if (lane == 0) { p_lds[j1] = i; u_lds[i] = usum; }
        __syncthreads();
    }

    // out[b][k] = p[k+1] - 1 for the K real columns
    for (int j = lane; j < K_; j += 64)
        out[b * K_ + j] = p_lds[j + 1] - 1;
}

// ------------------------------------------------------------------- launcher
extern "C" void kernel_launch(void* const* d_in, const int* in_sizes, int n_in,
                              void* d_out, int out_size, void* d_ws, size_t ws_size,
                              hipStream_t stream) {
    const float* mp = (const float*)d_in[0];   // meta_points
    const float* mv = (const float*)d_in[1];   // meta_visibles
    /* d_in[2] covisibles: unused by reference */
    const float* gt = (const float*)d_in[3];   // gtpoints
    const float* gv = (const float*)d_in[4];   // gtvisibles
    int* out = (int*)d_out;                    // int32 assignment indices
    float* cost = (float*)d_ws;                // 16*256*128 fp32 = 2 MB

    dim3 gridA(B_, M_);
    cost_kernel<<<gridA, K_, 0, stream>>>(mp, mv, gt, gv, cost);
    match_kernel<<<B_, 64, 0, stream>>>(cost, out);
}